// Round 5
// baseline (837.061 us; speedup 1.0000x reference)
//
#include <hip/hip_runtime.h>
#include <cstdint>
#include <cstddef>

typedef unsigned short u16;
typedef unsigned int u32;

__device__ __forceinline__ u16 f2b(float f) {
    u32 b = __float_as_uint(f);
    b += 0x7fffu + ((b >> 16) & 1u);   // RNE
    return (u16)(b >> 16);
}
__device__ __forceinline__ float b2f(u16 u) {
    return __uint_as_float(((u32)u) << 16);
}

// ================= u-precompute: u31 = W31@Wr3[0:64], u32 = W32@Wr3[64:128], c3 =================
__global__ void uprep(const float* __restrict__ W31, const float* __restrict__ W32,
                      const float* __restrict__ b31, const float* __restrict__ b32,
                      const float* __restrict__ Wr3, const float* __restrict__ br3,
                      float* __restrict__ u31, float* __restrict__ u32, float* __restrict__ c3) {
    __shared__ float s[64];
    int t = threadIdx.x;
    if (t < 128) {
        float a = 0.f, b = 0.f;
        for (int c = 0; c < 64; ++c) {
            a = fmaf(W31[t * 64 + c], Wr3[c], a);
            b = fmaf(W32[t * 64 + c], Wr3[64 + c], b);
        }
        u31[t] = a;
        u32[t] = b;
    }
    if (t < 64) s[t] = b31[t] * Wr3[t] + b32[t] * Wr3[64 + t];
    __syncthreads();
    if (t < 32) s[t] += s[t + 32];
    __syncthreads();
    if (t == 0) {
        float acc = 0.f;
        for (int i = 0; i < 32; ++i) acc += s[i];
        c3[0] = acc + br3[0];
    }
}

// ================= CSR build =================
__global__ void degcnt_all(const int* __restrict__ c1, const int* __restrict__ c2,
                           int* __restrict__ degc, int N, int E1, int E2) {
    int e = blockIdx.x * blockDim.x + threadIdx.x;
    if (e < E1) atomicAdd(&degc[c1[e]], 1);
    else if (e < E1 + E2) atomicAdd(&degc[N + c2[e - E1]], 1);
}

__global__ void dinv_fin(const int* __restrict__ degc, float* __restrict__ d1,
                         float* __restrict__ d2, int n) {
    int i = blockIdx.x * blockDim.x + threadIdx.x;
    if (i < n) {
        int a = degc[i], b = degc[n + i];
        d1[i] = a > 0 ? rsqrtf((float)a) : 0.f;
        d2[i] = b > 0 ? rsqrtf((float)b) : 0.f;
    }
}

__global__ void scan1(const int* __restrict__ deg, int* __restrict__ partial, int n) {
    __shared__ int s[256];
    int i = blockIdx.x * 256 + threadIdx.x;
    s[threadIdx.x] = (i < n) ? deg[i] : 0;
    __syncthreads();
    for (int off = 128; off > 0; off >>= 1) {
        if (threadIdx.x < off) s[threadIdx.x] += s[threadIdx.x + off];
        __syncthreads();
    }
    if (threadIdx.x == 0) partial[blockIdx.x] = s[0];
}

__global__ void scan2(int* __restrict__ partial, int nb, int* __restrict__ starts, int n) {
    __shared__ int s[512];
    int t = threadIdx.x;
    int v = (t < nb) ? partial[t] : 0;
    s[t] = v;
    __syncthreads();
    for (int off = 1; off < 512; off <<= 1) {
        int u = (t >= off) ? s[t - off] : 0;
        __syncthreads();
        s[t] += u;
        __syncthreads();
    }
    if (t < nb) partial[t] = s[t] - v;
    if (t == 511) starts[n] = s[511];
}

__global__ void scan3(const int* __restrict__ deg, const int* __restrict__ partial,
                      int* __restrict__ starts, int n) {
    __shared__ int s[256];
    int i = blockIdx.x * 256 + threadIdx.x;
    int v = (i < n) ? deg[i] : 0;
    s[threadIdx.x] = v;
    __syncthreads();
    for (int off = 1; off < 256; off <<= 1) {
        int u = (threadIdx.x >= off) ? s[threadIdx.x - off] : 0;
        __syncthreads();
        s[threadIdx.x] += u;
        __syncthreads();
    }
    if (i < n) starts[i] = partial[blockIdx.x] + s[threadIdx.x] - v;
}

// fill CSR slots; reuses degc as countdown cursor (degc dead after scans)
__global__ void csr_fill_all(const int* __restrict__ ei1, const int* __restrict__ ei2,
                             const float* __restrict__ dinv1, const float* __restrict__ dinv2,
                             const int* __restrict__ starts, int* __restrict__ degc,
                             int2* __restrict__ csr, int N, int E1, int E2) {
    int e = blockIdx.x * blockDim.x + threadIdx.x;
    int r, c, base;
    const float* dinv;
    if (e < E1) { r = ei1[e]; c = ei1[E1 + e]; base = 0; dinv = dinv1; }
    else if (e < E1 + E2) { int t = e - E1; r = ei2[t]; c = ei2[E2 + t]; base = N; dinv = dinv2; }
    else return;
    int pos = starts[base + c] + atomicSub(&degc[base + c], 1) - 1;
    csr[pos] = make_int2(r, __float_as_int(dinv[r] * dinv[c]));
}

// ================= mm_in: R0 = relu(x@W_in + b_in); fused readout0 + outacc init =================
__global__ __launch_bounds__(256) void mm_in(const float* __restrict__ A, const float* __restrict__ W,
                                             const float* __restrict__ bias, float* __restrict__ C,
                                             const float* __restrict__ Wr0, const float* __restrict__ br0,
                                             const float* __restrict__ br1, const float* __restrict__ br2,
                                             const float* __restrict__ w0, const float* __restrict__ w1,
                                             const float* __restrict__ w2, const float* __restrict__ w3,
                                             const float* __restrict__ c3, float* __restrict__ outacc,
                                             int n) {
    __shared__ float As[64][68];
    __shared__ float Ws[64][68];
    const int tid = threadIdx.x;
    const int r0 = blockIdx.x * 64;

    for (int idx = tid; idx < 64 * 16; idx += 256) {
        int k = idx >> 4, cq = (idx & 15) * 4;
        *(float4*)&Ws[k][cq] = *(const float4*)&W[k * 64 + cq];
    }

    const int tr = (tid >> 4) * 4;
    const int tc = (tid & 15) * 4;
    float4 acc0 = {0,0,0,0}, acc1 = {0,0,0,0}, acc2 = {0,0,0,0}, acc3 = {0,0,0,0};

    __syncthreads();
#pragma unroll
    for (int it = 0; it < 4; ++it) {
        int r = (tid >> 4) + it * 16;
        int cq = (tid & 15) * 4;
        int gr = r0 + r;
        float4 v = {0,0,0,0};
        if (gr < n) v = *(const float4*)&A[(size_t)gr * 64 + cq];
        *(float4*)&As[r][cq] = v;
    }
    __syncthreads();
#pragma unroll
    for (int k = 0; k < 64; k += 4) {
        float4 a0 = *(const float4*)&As[tr + 0][k];
        float4 a1 = *(const float4*)&As[tr + 1][k];
        float4 a2 = *(const float4*)&As[tr + 2][k];
        float4 a3 = *(const float4*)&As[tr + 3][k];
        float4 b0 = *(const float4*)&Ws[k + 0][tc];
        float4 b1 = *(const float4*)&Ws[k + 1][tc];
        float4 b2 = *(const float4*)&Ws[k + 2][tc];
        float4 b3 = *(const float4*)&Ws[k + 3][tc];
#define DK(comp, B)                                                                   \
        acc0.x = fmaf(a0.comp, B.x, acc0.x); acc0.y = fmaf(a0.comp, B.y, acc0.y);     \
        acc0.z = fmaf(a0.comp, B.z, acc0.z); acc0.w = fmaf(a0.comp, B.w, acc0.w);     \
        acc1.x = fmaf(a1.comp, B.x, acc1.x); acc1.y = fmaf(a1.comp, B.y, acc1.y);     \
        acc1.z = fmaf(a1.comp, B.z, acc1.z); acc1.w = fmaf(a1.comp, B.w, acc1.w);     \
        acc2.x = fmaf(a2.comp, B.x, acc2.x); acc2.y = fmaf(a2.comp, B.y, acc2.y);     \
        acc2.z = fmaf(a2.comp, B.z, acc2.z); acc2.w = fmaf(a2.comp, B.w, acc2.w);     \
        acc3.x = fmaf(a3.comp, B.x, acc3.x); acc3.y = fmaf(a3.comp, B.y, acc3.y);     \
        acc3.z = fmaf(a3.comp, B.z, acc3.z); acc3.w = fmaf(a3.comp, B.w, acc3.w);
        DK(x, b0) DK(y, b1) DK(z, b2) DK(w, b3)
#undef DK
    }

    float4 bv = *(const float4*)&bias[tc];
    float4 wr = *(const float4*)&Wr0[tc];
    float4 accs[4] = {acc0, acc1, acc2, acc3};
    float part[4];
#pragma unroll
    for (int i = 0; i < 4; ++i) {
        float4 v = accs[i];
        v.x = fmaxf(v.x + bv.x, 0.f); v.y = fmaxf(v.y + bv.y, 0.f);
        v.z = fmaxf(v.z + bv.z, 0.f); v.w = fmaxf(v.w + bv.w, 0.f);
        int gr = r0 + tr + i;
        if (gr < n) *(float4*)&C[(size_t)gr * 64 + tc] = v;
        part[i] = v.x * wr.x + v.y * wr.y + v.z * wr.z + v.w * wr.w;
    }
    // reduce each part[i] over the 16 lanes of this row group (consecutive lanes)
#pragma unroll
    for (int off = 8; off > 0; off >>= 1) {
#pragma unroll
        for (int i = 0; i < 4; ++i) part[i] += __shfl_down(part[i], off);
    }
    if ((tid & 15) == 0) {
        float W0 = w0[0];
        float CONST = W0 * br0[0] + w1[0] * br1[0] + w2[0] * br2[0] + w3[0] * c3[0];
#pragma unroll
        for (int i = 0; i < 4; ++i) {
            int gr = r0 + tr + i;
            if (gr < n) outacc[gr] = W0 * part[i] + CONST;
        }
    }
}

// ================= mmpair: Y16[:,0:64] = A@Wa, Y16[:,64:128] = A@Wb (bf16 out) =================
template <int K>
__global__ __launch_bounds__(256) void mmpair(const float* __restrict__ A,
                                              const float* __restrict__ WA,
                                              const float* __restrict__ WB,
                                              u16* __restrict__ Y16, int n) {
    __shared__ float As[64][68];
    __shared__ float Wa[64][68];
    __shared__ float Wb[64][68];
    const int tid = threadIdx.x;
    const int r0 = blockIdx.x * 64;
    const int tr = (tid >> 4) * 4;
    const int tc = (tid & 15) * 4;
    float4 aA0 = {0,0,0,0}, aA1 = {0,0,0,0}, aA2 = {0,0,0,0}, aA3 = {0,0,0,0};
    float4 aB0 = {0,0,0,0}, aB1 = {0,0,0,0}, aB2 = {0,0,0,0}, aB3 = {0,0,0,0};

    for (int kb = 0; kb < K; kb += 64) {
        __syncthreads();
        for (int idx = tid; idx < 64 * 16; idx += 256) {
            int k = idx >> 4, cq = (idx & 15) * 4;
            *(float4*)&Wa[k][cq] = *(const float4*)&WA[(kb + k) * 64 + cq];
            *(float4*)&Wb[k][cq] = *(const float4*)&WB[(kb + k) * 64 + cq];
        }
#pragma unroll
        for (int it = 0; it < 4; ++it) {
            int r = (tid >> 4) + it * 16;
            int cq = (tid & 15) * 4;
            int gr = r0 + r;
            float4 v = {0,0,0,0};
            if (gr < n) v = *(const float4*)&A[(size_t)gr * K + kb + cq];
            *(float4*)&As[r][cq] = v;
        }
        __syncthreads();
#pragma unroll
        for (int k = 0; k < 64; k += 4) {
            float4 a0 = *(const float4*)&As[tr + 0][k];
            float4 a1 = *(const float4*)&As[tr + 1][k];
            float4 a2 = *(const float4*)&As[tr + 2][k];
            float4 a3 = *(const float4*)&As[tr + 3][k];
#define DKP(comp, kk)                                                                   \
            {                                                                           \
                float4 B = *(const float4*)&Wa[kk][tc];                                 \
                float4 Cq = *(const float4*)&Wb[kk][tc];                                \
                aA0.x = fmaf(a0.comp, B.x, aA0.x); aA0.y = fmaf(a0.comp, B.y, aA0.y);   \
                aA0.z = fmaf(a0.comp, B.z, aA0.z); aA0.w = fmaf(a0.comp, B.w, aA0.w);   \
                aA1.x = fmaf(a1.comp, B.x, aA1.x); aA1.y = fmaf(a1.comp, B.y, aA1.y);   \
                aA1.z = fmaf(a1.comp, B.z, aA1.z); aA1.w = fmaf(a1.comp, B.w, aA1.w);   \
                aA2.x = fmaf(a2.comp, B.x, aA2.x); aA2.y = fmaf(a2.comp, B.y, aA2.y);   \
                aA2.z = fmaf(a2.comp, B.z, aA2.z); aA2.w = fmaf(a2.comp, B.w, aA2.w);   \
                aA3.x = fmaf(a3.comp, B.x, aA3.x); aA3.y = fmaf(a3.comp, B.y, aA3.y);   \
                aA3.z = fmaf(a3.comp, B.z, aA3.z); aA3.w = fmaf(a3.comp, B.w, aA3.w);   \
                aB0.x = fmaf(a0.comp, Cq.x, aB0.x); aB0.y = fmaf(a0.comp, Cq.y, aB0.y); \
                aB0.z = fmaf(a0.comp, Cq.z, aB0.z); aB0.w = fmaf(a0.comp, Cq.w, aB0.w); \
                aB1.x = fmaf(a1.comp, Cq.x, aB1.x); aB1.y = fmaf(a1.comp, Cq.y, aB1.y); \
                aB1.z = fmaf(a1.comp, Cq.z, aB1.z); aB1.w = fmaf(a1.comp, Cq.w, aB1.w); \
                aB2.x = fmaf(a2.comp, Cq.x, aB2.x); aB2.y = fmaf(a2.comp, Cq.y, aB2.y); \
                aB2.z = fmaf(a2.comp, Cq.z, aB2.z); aB2.w = fmaf(a2.comp, Cq.w, aB2.w); \
                aB3.x = fmaf(a3.comp, Cq.x, aB3.x); aB3.y = fmaf(a3.comp, Cq.y, aB3.y); \
                aB3.z = fmaf(a3.comp, Cq.z, aB3.z); aB3.w = fmaf(a3.comp, Cq.w, aB3.w); \
            }
            DKP(x, k + 0) DKP(y, k + 1) DKP(z, k + 2) DKP(w, k + 3)
#undef DKP
        }
    }

    float4 As4[4] = {aA0, aA1, aA2, aA3};
    float4 Bs4[4] = {aB0, aB1, aB2, aB3};
#pragma unroll
    for (int i = 0; i < 4; ++i) {
        int gr = r0 + tr + i;
        if (gr < n) {
            ushort4 oa, ob;
            oa.x = f2b(As4[i].x); oa.y = f2b(As4[i].y); oa.z = f2b(As4[i].z); oa.w = f2b(As4[i].w);
            ob.x = f2b(Bs4[i].x); ob.y = f2b(Bs4[i].y); ob.z = f2b(Bs4[i].z); ob.w = f2b(Bs4[i].w);
            *(ushort4*)&Y16[(size_t)gr * 128 + tc] = oa;
            *(ushort4*)&Y16[(size_t)gr * 128 + 64 + tc] = ob;
        }
    }
}

// ================= gather + fused readout =================
// wave = (dest, set); lanes 0-31 channels pairs of even edges, 32-63 odd edges.
__global__ __launch_bounds__(256) void gatherRO(const int* __restrict__ starts,
                                                const int2* __restrict__ csr,
                                                const u16* __restrict__ Y16,
                                                const float* __restrict__ bA,
                                                const float* __restrict__ bB,
                                                float* __restrict__ dest,
                                                const float* __restrict__ Wr,
                                                const float* __restrict__ wl,
                                                float* __restrict__ outacc, int N) {
    int wave = (blockIdx.x * blockDim.x + threadIdx.x) >> 6;
    int lane = threadIdx.x & 63;
    if (wave >= 2 * N) return;
    int set2 = wave >= N;
    int d = set2 ? wave - N : wave;
    int base = set2 ? N : 0;
    int yoff = set2 ? 64 : 0;
    int half = lane >> 5;       // 0 or 1
    int m = lane & 31;          // channel-pair index

    int s0 = __builtin_amdgcn_readfirstlane(starts[base + d]);
    int s1 = __builtin_amdgcn_readfirstlane(starts[base + d + 1]);

    float ax = 0.f, ay = 0.f;
    int j = s0;
    for (; j + 4 <= s1; j += 4) {
        int2 e0 = csr[j + half];
        int2 e1 = csr[j + 2 + half];
        u32 y0 = *(const u32*)&Y16[(size_t)e0.x * 128 + yoff + 2 * m];
        u32 y1 = *(const u32*)&Y16[(size_t)e1.x * 128 + yoff + 2 * m];
        float w0 = __int_as_float(e0.y), w1 = __int_as_float(e1.y);
        ax = fmaf(w0, b2f((u16)y0), ax); ay = fmaf(w0, b2f((u16)(y0 >> 16)), ay);
        ax = fmaf(w1, b2f((u16)y1), ax); ay = fmaf(w1, b2f((u16)(y1 >> 16)), ay);
    }
    if (j + 2 <= s1) {
        int2 e = csr[j + half];
        u32 y = *(const u32*)&Y16[(size_t)e.x * 128 + yoff + 2 * m];
        float w = __int_as_float(e.y);
        ax = fmaf(w, b2f((u16)y), ax); ay = fmaf(w, b2f((u16)(y >> 16)), ay);
        j += 2;
    }
    if (j < s1 && half == 0) {
        int2 e = csr[j];
        u32 y = *(const u32*)&Y16[(size_t)e.x * 128 + yoff + 2 * m];
        float w = __int_as_float(e.y);
        ax = fmaf(w, b2f((u16)y), ax); ay = fmaf(w, b2f((u16)(y >> 16)), ay);
    }
    // combine halves
    ax += __shfl_down(ax, 32);
    ay += __shfl_down(ay, 32);

    if (half == 0) {
        const float* bias = set2 ? bB : bA;
        float bx = bias[2 * m], by = bias[2 * m + 1];
        float vx = ax + bx, vy = ay + by;
        *(float2*)&dest[(size_t)d * 128 + yoff + 2 * m] = make_float2(vx, vy);
        // fused readout partial: sum_c v[c]*Wr[yoff+c]
        float p = vx * Wr[yoff + 2 * m] + vy * Wr[yoff + 2 * m + 1];
#pragma unroll
        for (int off = 16; off > 0; off >>= 1) p += __shfl_down(p, off);
        if (m == 0) atomicAdd(&outacc[d], wl[0] * p);
    }
}

// ================= zpair: z1 = w3*(Q @ u31), z2 = w3*(Q @ u32); one wave per node =================
__global__ __launch_bounds__(256) void zpair(const float* __restrict__ Q,
                                             const float* __restrict__ u31,
                                             const float* __restrict__ u32,
                                             const float* __restrict__ w3,
                                             float* __restrict__ z1, float* __restrict__ z2, int N) {
    int node = (blockIdx.x * blockDim.x + threadIdx.x) >> 6;
    int lane = threadIdx.x & 63;
    if (node >= N) return;
    float q0 = Q[(size_t)node * 128 + lane];
    float q1 = Q[(size_t)node * 128 + 64 + lane];
    float p1 = q0 * u31[lane] + q1 * u31[64 + lane];
    float p2 = q0 * u32[lane] + q1 * u32[64 + lane];
#pragma unroll
    for (int off = 32; off > 0; off >>= 1) {
        p1 += __shfl_down(p1, off);
        p2 += __shfl_down(p2, off);
    }
    if (lane == 0) {
        float W3 = w3[0];
        z1[node] = W3 * p1;
        z2[node] = W3 * p2;
    }
}

// ================= edge3: outacc[c] += wt * z[r] (scalar per-edge) =================
__global__ void edge3(const int* __restrict__ ei1, const int* __restrict__ ei2,
                      const float* __restrict__ dinv1, const float* __restrict__ dinv2,
                      const float* __restrict__ z1, const float* __restrict__ z2,
                      float* __restrict__ outacc, int E1, int E2) {
    int e = blockIdx.x * blockDim.x + threadIdx.x;
    int r, c;
    const float *dinv, *z;
    if (e < E1) { r = ei1[e]; c = ei1[E1 + e]; dinv = dinv1; z = z1; }
    else if (e < E1 + E2) { int t = e - E1; r = ei2[t]; c = ei2[E2 + t]; dinv = dinv2; z = z2; }
    else return;
    atomicAdd(&outacc[c], dinv[r] * dinv[c] * z[r]);
}

__global__ void finalize(const float* __restrict__ outacc, float* __restrict__ out, int N) {
    int i = blockIdx.x * blockDim.x + threadIdx.x;
    if (i < N) out[i] = outacc[i];
}

// ================= host =================
static inline char* carve(char*& p, size_t bytes) {
    char* r = p;
    p += (bytes + 255) & ~(size_t)255;
    return r;
}

extern "C" void kernel_launch(void* const* d_in, const int* in_sizes, int n_in,
                              void* d_out, int out_size, void* d_ws, size_t ws_size,
                              hipStream_t stream) {
    const float* x    = (const float*)d_in[0];
    const int*   ei1  = (const int*)d_in[1];
    const int*   ei2  = (const int*)d_in[2];
    const float* W_in = (const float*)d_in[3];  const float* b_in = (const float*)d_in[4];
    const float* W11  = (const float*)d_in[5];
    const float* b11  = (const float*)d_in[6];
    const float* W12  = (const float*)d_in[7];  const float* b12  = (const float*)d_in[8];
    const float* W21  = (const float*)d_in[9];  const float* b21  = (const float*)d_in[10];
    const float* W22  = (const float*)d_in[11]; const float* b22  = (const float*)d_in[12];
    const float* W31  = (const float*)d_in[13]; const float* b31  = (const float*)d_in[14];
    const float* W32  = (const float*)d_in[15]; const float* b32  = (const float*)d_in[16];
    const float* Wr0  = (const float*)d_in[17]; const float* br0  = (const float*)d_in[18];
    const float* Wr1  = (const float*)d_in[19]; const float* br1  = (const float*)d_in[20];
    const float* Wr2  = (const float*)d_in[21]; const float* br2  = (const float*)d_in[22];
    const float* Wr3  = (const float*)d_in[23]; const float* br3  = (const float*)d_in[24];
    const float* w0   = (const float*)d_in[25];
    const float* w1   = (const float*)d_in[26];
    const float* w2   = (const float*)d_in[27];
    const float* w3   = (const float*)d_in[28];

    const int N  = in_sizes[0] / 64;   // 50000
    const int E1 = in_sizes[1] / 2;    // 800000
    const int E2 = in_sizes[2] / 2;
    const int N2 = 2 * N;

    char* p = (char*)d_ws;
    float* dinv1   = (float*)carve(p, (size_t)N * 4);
    float* dinv2   = (float*)carve(p, (size_t)N * 4);
    int*   degc    = (int*)  carve(p, (size_t)N2 * 4);
    int*   starts  = (int*)  carve(p, ((size_t)N2 + 1) * 4);
    int*   partial = (int*)  carve(p, 512 * 4);
    float* uws     = (float*)carve(p, (128 + 128 + 1) * 4);  // u31, u32, c3
    float* z1      = (float*)carve(p, (size_t)N * 4);
    float* z2      = (float*)carve(p, (size_t)N * 4);
    int2*  csr     = (int2*) carve(p, (size_t)(E1 + E2) * 8);
    float* R0      = (float*)carve(p, (size_t)N * 64 * 4);
    float* P       = (float*)carve(p, (size_t)N * 128 * 4);
    float* Q       = (float*)carve(p, (size_t)N * 128 * 4);
    float* outacc  = (float*)carve(p, (size_t)N * 4);
    float* u31 = uws, *u32v = uws + 128, *c3 = uws + 256;
    // bf16 Y (N x 128 u16 = 12.8 MB) aliases dead fp32 slots:
    u16* Y16_L1  = (u16*)Q;    // layer-1: Q not yet live
    u16* Y16_L2  = (u16*)R0;   // layer-2: R0 dead after layer-1 mmpair
    (void)ws_size; (void)n_in; (void)out_size;

    const int B = 256;
    dim3 blk(B);
    int gN   = (N + B - 1) / B;
    int gE   = (E1 + E2 + B - 1) / B;
    int gMM  = (N + 63) / 64;
    int gGa  = (int)(((long long)N2 * 64 + B - 1) / B);
    int gZ   = (N * 64 + B - 1) / B;
    int nb   = (N2 + 255) / 256;

    // ---- CSR build + u-precompute ----
    hipMemsetAsync(degc, 0, (size_t)N2 * 4, stream);
    uprep<<<1, 128, 0, stream>>>(W31, W32, b31, b32, Wr3, br3, u31, u32v, c3);
    degcnt_all<<<gE, blk, 0, stream>>>(ei1 + E1, ei2 + E2, degc, N, E1, E2);
    dinv_fin<<<gN, blk, 0, stream>>>(degc, dinv1, dinv2, N);
    scan1<<<nb, blk, 0, stream>>>(degc, partial, N2);
    scan2<<<1, 512, 0, stream>>>(partial, nb, starts, N2);
    scan3<<<nb, blk, 0, stream>>>(degc, partial, starts, N2);
    csr_fill_all<<<gE, blk, 0, stream>>>(ei1, ei2, dinv1, dinv2, starts, degc, csr, N, E1, E2);

    // ---- R0 = relu(x @ W_in + b_in); outacc = w0*readout0 + CONST ----
    mm_in<<<gMM, blk, 0, stream>>>(x, W_in, b_in, R0, Wr0, br0, br1, br2,
                                   w0, w1, w2, w3, c3, outacc, N);

    // ---- layer 1 ----
    mmpair<64><<<gMM, blk, 0, stream>>>(R0, W11, W12, Y16_L1, N);
    gatherRO<<<gGa, blk, 0, stream>>>(starts, csr, Y16_L1, b11, b12, P, Wr1, w1, outacc, N);

    // ---- layer 2 ----
    mmpair<128><<<gMM, blk, 0, stream>>>(P, W21, W22, Y16_L2, N);
    gatherRO<<<gGa, blk, 0, stream>>>(starts, csr, Y16_L2, b21, b22, Q, Wr2, w2, outacc, N);

    // ---- layer 3 (algebraic shortcut): out3 = w3*(sum_e wt*z[src] + c3) ----
    zpair<<<gZ, blk, 0, stream>>>(Q, u31, u32v, w3, z1, z2, N);
    edge3<<<gE, blk, 0, stream>>>(ei1, ei2, dinv1, dinv2, z1, z2, outacc, E1, E2);
    finalize<<<gN, blk, 0, stream>>>(outacc, (float*)d_out, N);
}

// Round 6
// 626.002 us; speedup vs baseline: 1.3372x; 1.3372x over previous
//
#include <hip/hip_runtime.h>
#include <cstdint>
#include <cstddef>

typedef unsigned short u16;
typedef unsigned int u32;

__device__ __forceinline__ u16 f2b(float f) {
    u32 b = __float_as_uint(f);
    b += 0x7fffu + ((b >> 16) & 1u);   // RNE
    return (u16)(b >> 16);
}
__device__ __forceinline__ float b2f(u16 u) {
    return __uint_as_float(((u32)u) << 16);
}

// ================= u-precompute: u31 = W31@Wr3[0:64], u32 = W32@Wr3[64:128], c3 =================
__global__ void uprep(const float* __restrict__ W31, const float* __restrict__ W32,
                      const float* __restrict__ b31, const float* __restrict__ b32,
                      const float* __restrict__ Wr3, const float* __restrict__ br3,
                      float* __restrict__ u31, float* __restrict__ u32, float* __restrict__ c3) {
    __shared__ float s[64];
    int t = threadIdx.x;
    if (t < 128) {
        float a = 0.f, b = 0.f;
        for (int c = 0; c < 64; ++c) {
            a = fmaf(W31[t * 64 + c], Wr3[c], a);
            b = fmaf(W32[t * 64 + c], Wr3[64 + c], b);
        }
        u31[t] = a;
        u32[t] = b;
    }
    if (t < 64) s[t] = b31[t] * Wr3[t] + b32[t] * Wr3[64 + t];
    __syncthreads();
    if (t < 32) s[t] += s[t + 32];
    __syncthreads();
    if (t == 0) {
        float acc = 0.f;
        for (int i = 0; i < 32; ++i) acc += s[i];
        c3[0] = acc + br3[0];
    }
}

// ================= CSR build =================
__global__ void degcnt_all(const int* __restrict__ c1, const int* __restrict__ c2,
                           int* __restrict__ degc, int N, int E1, int E2) {
    int e = blockIdx.x * blockDim.x + threadIdx.x;
    if (e < E1) atomicAdd(&degc[c1[e]], 1);
    else if (e < E1 + E2) atomicAdd(&degc[N + c2[e - E1]], 1);
}

__global__ void dinv_fin(const int* __restrict__ degc, float* __restrict__ d1,
                         float* __restrict__ d2, int n) {
    int i = blockIdx.x * blockDim.x + threadIdx.x;
    if (i < n) {
        int a = degc[i], b = degc[n + i];
        d1[i] = a > 0 ? rsqrtf((float)a) : 0.f;
        d2[i] = b > 0 ? rsqrtf((float)b) : 0.f;
    }
}

__global__ void scan1(const int* __restrict__ deg, int* __restrict__ partial, int n) {
    __shared__ int s[256];
    int i = blockIdx.x * 256 + threadIdx.x;
    s[threadIdx.x] = (i < n) ? deg[i] : 0;
    __syncthreads();
    for (int off = 128; off > 0; off >>= 1) {
        if (threadIdx.x < off) s[threadIdx.x] += s[threadIdx.x + off];
        __syncthreads();
    }
    if (threadIdx.x == 0) partial[blockIdx.x] = s[0];
}

__global__ void scan2(int* __restrict__ partial, int nb, int* __restrict__ starts, int n) {
    __shared__ int s[512];
    int t = threadIdx.x;
    int v = (t < nb) ? partial[t] : 0;
    s[t] = v;
    __syncthreads();
    for (int off = 1; off < 512; off <<= 1) {
        int u = (t >= off) ? s[t - off] : 0;
        __syncthreads();
        s[t] += u;
        __syncthreads();
    }
    if (t < nb) partial[t] = s[t] - v;
    if (t == 511) starts[n] = s[511];
}

__global__ void scan3(const int* __restrict__ deg, const int* __restrict__ partial,
                      int* __restrict__ starts, int n) {
    __shared__ int s[256];
    int i = blockIdx.x * 256 + threadIdx.x;
    int v = (i < n) ? deg[i] : 0;
    s[threadIdx.x] = v;
    __syncthreads();
    for (int off = 1; off < 256; off <<= 1) {
        int u = (threadIdx.x >= off) ? s[threadIdx.x - off] : 0;
        __syncthreads();
        s[threadIdx.x] += u;
        __syncthreads();
    }
    if (i < n) starts[i] = partial[blockIdx.x] + s[threadIdx.x] - v;
}

// fill CSR slots; reuses degc as countdown cursor (degc dead after scans)
__global__ void csr_fill_all(const int* __restrict__ ei1, const int* __restrict__ ei2,
                             const float* __restrict__ dinv1, const float* __restrict__ dinv2,
                             const int* __restrict__ starts, int* __restrict__ degc,
                             int2* __restrict__ csr, int N, int E1, int E2) {
    int e = blockIdx.x * blockDim.x + threadIdx.x;
    int r, c, base;
    const float* dinv;
    if (e < E1) { r = ei1[e]; c = ei1[E1 + e]; base = 0; dinv = dinv1; }
    else if (e < E1 + E2) { int t = e - E1; r = ei2[t]; c = ei2[E2 + t]; base = N; dinv = dinv2; }
    else return;
    int pos = starts[base + c] + atomicSub(&degc[base + c], 1) - 1;
    csr[pos] = make_int2(r, __float_as_int(dinv[r] * dinv[c]));
}

// ================= mm_in: R0 = relu(x@W_in + b_in); fused readout0 + outacc init =================
__global__ __launch_bounds__(256) void mm_in(const float* __restrict__ A, const float* __restrict__ W,
                                             const float* __restrict__ bias, float* __restrict__ C,
                                             const float* __restrict__ Wr0, const float* __restrict__ br0,
                                             const float* __restrict__ br1, const float* __restrict__ br2,
                                             const float* __restrict__ w0, const float* __restrict__ w1,
                                             const float* __restrict__ w2, const float* __restrict__ w3,
                                             const float* __restrict__ c3, float* __restrict__ outacc,
                                             int n) {
    __shared__ float As[64][68];
    __shared__ float Ws[64][68];
    const int tid = threadIdx.x;
    const int r0 = blockIdx.x * 64;

    for (int idx = tid; idx < 64 * 16; idx += 256) {
        int k = idx >> 4, cq = (idx & 15) * 4;
        *(float4*)&Ws[k][cq] = *(const float4*)&W[k * 64 + cq];
    }

    const int tr = (tid >> 4) * 4;
    const int tc = (tid & 15) * 4;
    float4 acc0 = {0,0,0,0}, acc1 = {0,0,0,0}, acc2 = {0,0,0,0}, acc3 = {0,0,0,0};

    __syncthreads();
#pragma unroll
    for (int it = 0; it < 4; ++it) {
        int r = (tid >> 4) + it * 16;
        int cq = (tid & 15) * 4;
        int gr = r0 + r;
        float4 v = {0,0,0,0};
        if (gr < n) v = *(const float4*)&A[(size_t)gr * 64 + cq];
        *(float4*)&As[r][cq] = v;
    }
    __syncthreads();
#pragma unroll
    for (int k = 0; k < 64; k += 4) {
        float4 a0 = *(const float4*)&As[tr + 0][k];
        float4 a1 = *(const float4*)&As[tr + 1][k];
        float4 a2 = *(const float4*)&As[tr + 2][k];
        float4 a3 = *(const float4*)&As[tr + 3][k];
        float4 b0 = *(const float4*)&Ws[k + 0][tc];
        float4 b1 = *(const float4*)&Ws[k + 1][tc];
        float4 b2 = *(const float4*)&Ws[k + 2][tc];
        float4 b3 = *(const float4*)&Ws[k + 3][tc];
#define DK(comp, B)                                                                   \
        acc0.x = fmaf(a0.comp, B.x, acc0.x); acc0.y = fmaf(a0.comp, B.y, acc0.y);     \
        acc0.z = fmaf(a0.comp, B.z, acc0.z); acc0.w = fmaf(a0.comp, B.w, acc0.w);     \
        acc1.x = fmaf(a1.comp, B.x, acc1.x); acc1.y = fmaf(a1.comp, B.y, acc1.y);     \
        acc1.z = fmaf(a1.comp, B.z, acc1.z); acc1.w = fmaf(a1.comp, B.w, acc1.w);     \
        acc2.x = fmaf(a2.comp, B.x, acc2.x); acc2.y = fmaf(a2.comp, B.y, acc2.y);     \
        acc2.z = fmaf(a2.comp, B.z, acc2.z); acc2.w = fmaf(a2.comp, B.w, acc2.w);     \
        acc3.x = fmaf(a3.comp, B.x, acc3.x); acc3.y = fmaf(a3.comp, B.y, acc3.y);     \
        acc3.z = fmaf(a3.comp, B.z, acc3.z); acc3.w = fmaf(a3.comp, B.w, acc3.w);
        DK(x, b0) DK(y, b1) DK(z, b2) DK(w, b3)
#undef DK
    }

    float4 bv = *(const float4*)&bias[tc];
    float4 wr = *(const float4*)&Wr0[tc];
    float4 accs[4] = {acc0, acc1, acc2, acc3};
    float part[4];
#pragma unroll
    for (int i = 0; i < 4; ++i) {
        float4 v = accs[i];
        v.x = fmaxf(v.x + bv.x, 0.f); v.y = fmaxf(v.y + bv.y, 0.f);
        v.z = fmaxf(v.z + bv.z, 0.f); v.w = fmaxf(v.w + bv.w, 0.f);
        int gr = r0 + tr + i;
        if (gr < n) *(float4*)&C[(size_t)gr * 64 + tc] = v;
        part[i] = v.x * wr.x + v.y * wr.y + v.z * wr.z + v.w * wr.w;
    }
    // reduce each part[i] over the 16 lanes of this row group (consecutive lanes)
#pragma unroll
    for (int off = 8; off > 0; off >>= 1) {
#pragma unroll
        for (int i = 0; i < 4; ++i) part[i] += __shfl_down(part[i], off);
    }
    if ((tid & 15) == 0) {
        float W0 = w0[0];
        float CONST = W0 * br0[0] + w1[0] * br1[0] + w2[0] * br2[0] + w3[0] * c3[0];
#pragma unroll
        for (int i = 0; i < 4; ++i) {
            int gr = r0 + tr + i;
            if (gr < n) outacc[gr] = W0 * part[i] + CONST;
        }
    }
}

// ================= mm64b: Y16[:, coff:coff+64] = A @ W (bf16 out, row stride 128) =================
// R4-proven register shape: 4 float4 accumulators, one weight matrix per block.
template <int K>
__global__ __launch_bounds__(256) void mm64b(const float* __restrict__ A, const float* __restrict__ W,
                                             u16* __restrict__ Y16, int coff, int n) {
    __shared__ float As[64][68];
    __shared__ float Ws[K][68];
    const int tid = threadIdx.x;
    const int r0 = blockIdx.x * 64;

    for (int idx = tid; idx < K * 16; idx += 256) {
        int k = idx >> 4, cq = (idx & 15) * 4;
        *(float4*)&Ws[k][cq] = *(const float4*)&W[k * 64 + cq];
    }

    const int tr = (tid >> 4) * 4;
    const int tc = (tid & 15) * 4;
    float4 acc0 = {0,0,0,0}, acc1 = {0,0,0,0}, acc2 = {0,0,0,0}, acc3 = {0,0,0,0};

    for (int kb = 0; kb < K; kb += 64) {
        __syncthreads();  // first pass also covers Ws writes
#pragma unroll
        for (int it = 0; it < 4; ++it) {
            int r = (tid >> 4) + it * 16;
            int cq = (tid & 15) * 4;
            int gr = r0 + r;
            float4 v = {0,0,0,0};
            if (gr < n) v = *(const float4*)&A[(size_t)gr * K + kb + cq];
            *(float4*)&As[r][cq] = v;
        }
        __syncthreads();
#pragma unroll
        for (int k = 0; k < 64; k += 4) {
            float4 a0 = *(const float4*)&As[tr + 0][k];
            float4 a1 = *(const float4*)&As[tr + 1][k];
            float4 a2 = *(const float4*)&As[tr + 2][k];
            float4 a3 = *(const float4*)&As[tr + 3][k];
            float4 b0 = *(const float4*)&Ws[kb + k + 0][tc];
            float4 b1 = *(const float4*)&Ws[kb + k + 1][tc];
            float4 b2 = *(const float4*)&Ws[kb + k + 2][tc];
            float4 b3 = *(const float4*)&Ws[kb + k + 3][tc];
#define DK(comp, B)                                                                   \
            acc0.x = fmaf(a0.comp, B.x, acc0.x); acc0.y = fmaf(a0.comp, B.y, acc0.y); \
            acc0.z = fmaf(a0.comp, B.z, acc0.z); acc0.w = fmaf(a0.comp, B.w, acc0.w); \
            acc1.x = fmaf(a1.comp, B.x, acc1.x); acc1.y = fmaf(a1.comp, B.y, acc1.y); \
            acc1.z = fmaf(a1.comp, B.z, acc1.z); acc1.w = fmaf(a1.comp, B.w, acc1.w); \
            acc2.x = fmaf(a2.comp, B.x, acc2.x); acc2.y = fmaf(a2.comp, B.y, acc2.y); \
            acc2.z = fmaf(a2.comp, B.z, acc2.z); acc2.w = fmaf(a2.comp, B.w, acc2.w); \
            acc3.x = fmaf(a3.comp, B.x, acc3.x); acc3.y = fmaf(a3.comp, B.y, acc3.y); \
            acc3.z = fmaf(a3.comp, B.z, acc3.z); acc3.w = fmaf(a3.comp, B.w, acc3.w);
            DK(x, b0) DK(y, b1) DK(z, b2) DK(w, b3)
#undef DK
        }
    }

    float4 accs[4] = {acc0, acc1, acc2, acc3};
#pragma unroll
    for (int i = 0; i < 4; ++i) {
        int gr = r0 + tr + i;
        if (gr < n) {
            ushort4 o;
            o.x = f2b(accs[i].x); o.y = f2b(accs[i].y); o.z = f2b(accs[i].z); o.w = f2b(accs[i].w);
            *(ushort4*)&Y16[(size_t)gr * 128 + coff + tc] = o;
        }
    }
}

// ================= gather + fused readout =================
// wave = (dest, set); half-waves process even/odd edges; lane pairs 2 channels via u32.
__global__ __launch_bounds__(256) void gatherRO(const int* __restrict__ starts,
                                                const int2* __restrict__ csr,
                                                const u16* __restrict__ Y16,
                                                const float* __restrict__ bA,
                                                const float* __restrict__ bB,
                                                float* __restrict__ dest,
                                                const float* __restrict__ Wr,
                                                const float* __restrict__ wl,
                                                float* __restrict__ outacc, int N) {
    int wave = (blockIdx.x * blockDim.x + threadIdx.x) >> 6;
    int lane = threadIdx.x & 63;
    if (wave >= 2 * N) return;
    int set2 = wave >= N;
    int d = set2 ? wave - N : wave;
    int base = set2 ? N : 0;
    int yoff = set2 ? 64 : 0;
    int half = lane >> 5;       // 0 or 1
    int m = lane & 31;          // channel-pair index

    int s0 = __builtin_amdgcn_readfirstlane(starts[base + d]);
    int s1 = __builtin_amdgcn_readfirstlane(starts[base + d + 1]);

    float ax = 0.f, ay = 0.f;
    int j = s0;
    for (; j + 4 <= s1; j += 4) {
        int2 e0 = csr[j + half];
        int2 e1 = csr[j + 2 + half];
        u32 y0 = *(const u32*)&Y16[(size_t)e0.x * 128 + yoff + 2 * m];
        u32 y1 = *(const u32*)&Y16[(size_t)e1.x * 128 + yoff + 2 * m];
        float w0 = __int_as_float(e0.y), w1 = __int_as_float(e1.y);
        ax = fmaf(w0, b2f((u16)y0), ax); ay = fmaf(w0, b2f((u16)(y0 >> 16)), ay);
        ax = fmaf(w1, b2f((u16)y1), ax); ay = fmaf(w1, b2f((u16)(y1 >> 16)), ay);
    }
    if (j + 2 <= s1) {
        int2 e = csr[j + half];
        u32 y = *(const u32*)&Y16[(size_t)e.x * 128 + yoff + 2 * m];
        float w = __int_as_float(e.y);
        ax = fmaf(w, b2f((u16)y), ax); ay = fmaf(w, b2f((u16)(y >> 16)), ay);
        j += 2;
    }
    if (j < s1 && half == 0) {
        int2 e = csr[j];
        u32 y = *(const u32*)&Y16[(size_t)e.x * 128 + yoff + 2 * m];
        float w = __int_as_float(e.y);
        ax = fmaf(w, b2f((u16)y), ax); ay = fmaf(w, b2f((u16)(y >> 16)), ay);
    }
    // combine halves
    ax += __shfl_down(ax, 32);
    ay += __shfl_down(ay, 32);

    if (half == 0) {
        const float* bias = set2 ? bB : bA;
        float bx = bias[2 * m], by = bias[2 * m + 1];
        float vx = ax + bx, vy = ay + by;
        *(float2*)&dest[(size_t)d * 128 + yoff + 2 * m] = make_float2(vx, vy);
        // fused readout partial: sum_c v[c]*Wr[yoff+c]
        float p = vx * Wr[yoff + 2 * m] + vy * Wr[yoff + 2 * m + 1];
#pragma unroll
        for (int off = 16; off > 0; off >>= 1) p += __shfl_down(p, off);
        if (m == 0) atomicAdd(&outacc[d], wl[0] * p);
    }
}

// ================= zpair: z1 = w3*(Q @ u31), z2 = w3*(Q @ u32); one wave per node =================
__global__ __launch_bounds__(256) void zpair(const float* __restrict__ Q,
                                             const float* __restrict__ u31,
                                             const float* __restrict__ u32,
                                             const float* __restrict__ w3,
                                             float* __restrict__ z1, float* __restrict__ z2, int N) {
    int node = (blockIdx.x * blockDim.x + threadIdx.x) >> 6;
    int lane = threadIdx.x & 63;
    if (node >= N) return;
    float q0 = Q[(size_t)node * 128 + lane];
    float q1 = Q[(size_t)node * 128 + 64 + lane];
    float p1 = q0 * u31[lane] + q1 * u31[64 + lane];
    float p2 = q0 * u32[lane] + q1 * u32[64 + lane];
#pragma unroll
    for (int off = 32; off > 0; off >>= 1) {
        p1 += __shfl_down(p1, off);
        p2 += __shfl_down(p2, off);
    }
    if (lane == 0) {
        float W3 = w3[0];
        z1[node] = W3 * p1;
        z2[node] = W3 * p2;
    }
}

// ================= edge3: outacc[c] += wt * z[r] (scalar per-edge) =================
__global__ void edge3(const int* __restrict__ ei1, const int* __restrict__ ei2,
                      const float* __restrict__ dinv1, const float* __restrict__ dinv2,
                      const float* __restrict__ z1, const float* __restrict__ z2,
                      float* __restrict__ outacc, int E1, int E2) {
    int e = blockIdx.x * blockDim.x + threadIdx.x;
    int r, c;
    const float *dinv, *z;
    if (e < E1) { r = ei1[e]; c = ei1[E1 + e]; dinv = dinv1; z = z1; }
    else if (e < E1 + E2) { int t = e - E1; r = ei2[t]; c = ei2[E2 + t]; dinv = dinv2; z = z2; }
    else return;
    atomicAdd(&outacc[c], dinv[r] * dinv[c] * z[r]);
}

__global__ void finalize(const float* __restrict__ outacc, float* __restrict__ out, int N) {
    int i = blockIdx.x * blockDim.x + threadIdx.x;
    if (i < N) out[i] = outacc[i];
}

// ================= host =================
static inline char* carve(char*& p, size_t bytes) {
    char* r = p;
    p += (bytes + 255) & ~(size_t)255;
    return r;
}

extern "C" void kernel_launch(void* const* d_in, const int* in_sizes, int n_in,
                              void* d_out, int out_size, void* d_ws, size_t ws_size,
                              hipStream_t stream) {
    const float* x    = (const float*)d_in[0];
    const int*   ei1  = (const int*)d_in[1];
    const int*   ei2  = (const int*)d_in[2];
    const float* W_in = (const float*)d_in[3];  const float* b_in = (const float*)d_in[4];
    const float* W11  = (const float*)d_in[5];
    const float* b11  = (const float*)d_in[6];
    const float* W12  = (const float*)d_in[7];  const float* b12  = (const float*)d_in[8];
    const float* W21  = (const float*)d_in[9];  const float* b21  = (const float*)d_in[10];
    const float* W22  = (const float*)d_in[11]; const float* b22  = (const float*)d_in[12];
    const float* W31  = (const float*)d_in[13]; const float* b31  = (const float*)d_in[14];
    const float* W32  = (const float*)d_in[15]; const float* b32  = (const float*)d_in[16];
    const float* Wr0  = (const float*)d_in[17]; const float* br0  = (const float*)d_in[18];
    const float* Wr1  = (const float*)d_in[19]; const float* br1  = (const float*)d_in[20];
    const float* Wr2  = (const float*)d_in[21]; const float* br2  = (const float*)d_in[22];
    const float* Wr3  = (const float*)d_in[23]; const float* br3  = (const float*)d_in[24];
    const float* w0   = (const float*)d_in[25];
    const float* w1   = (const float*)d_in[26];
    const float* w2   = (const float*)d_in[27];
    const float* w3   = (const float*)d_in[28];

    const int N  = in_sizes[0] / 64;   // 50000
    const int E1 = in_sizes[1] / 2;    // 800000
    const int E2 = in_sizes[2] / 2;
    const int N2 = 2 * N;

    char* p = (char*)d_ws;
    float* dinv1   = (float*)carve(p, (size_t)N * 4);
    float* dinv2   = (float*)carve(p, (size_t)N * 4);
    int*   degc    = (int*)  carve(p, (size_t)N2 * 4);
    int*   starts  = (int*)  carve(p, ((size_t)N2 + 1) * 4);
    int*   partial = (int*)  carve(p, 512 * 4);
    float* uws     = (float*)carve(p, (128 + 128 + 1) * 4);  // u31, u32, c3
    float* z1      = (float*)carve(p, (size_t)N * 4);
    float* z2      = (float*)carve(p, (size_t)N * 4);
    int2*  csr     = (int2*) carve(p, (size_t)(E1 + E2) * 8);
    float* R0      = (float*)carve(p, (size_t)N * 64 * 4);
    float* P       = (float*)carve(p, (size_t)N * 128 * 4);
    float* Q       = (float*)carve(p, (size_t)N * 128 * 4);
    float* outacc  = (float*)carve(p, (size_t)N * 4);
    float* u31 = uws, *u32v = uws + 128, *c3 = uws + 256;
    // bf16 Y (N x 128 u16 = 12.8 MB) aliases dead fp32 slots:
    u16* Y16_L1  = (u16*)Q;    // layer-1: Q not yet live
    u16* Y16_L2  = (u16*)R0;   // layer-2: R0 dead after layer-1 mms
    (void)ws_size; (void)n_in; (void)out_size;

    const int B = 256;
    dim3 blk(B);
    int gN   = (N + B - 1) / B;
    int gE   = (E1 + E2 + B - 1) / B;
    int gMM  = (N + 63) / 64;
    int gGa  = (int)(((long long)N2 * 64 + B - 1) / B);
    int gZ   = (N * 64 + B - 1) / B;
    int nb   = (N2 + 255) / 256;

    // ---- CSR build + u-precompute ----
    hipMemsetAsync(degc, 0, (size_t)N2 * 4, stream);
    uprep<<<1, 128, 0, stream>>>(W31, W32, b31, b32, Wr3, br3, u31, u32v, c3);
    degcnt_all<<<gE, blk, 0, stream>>>(ei1 + E1, ei2 + E2, degc, N, E1, E2);
    dinv_fin<<<gN, blk, 0, stream>>>(degc, dinv1, dinv2, N);
    scan1<<<nb, blk, 0, stream>>>(degc, partial, N2);
    scan2<<<1, 512, 0, stream>>>(partial, nb, starts, N2);
    scan3<<<nb, blk, 0, stream>>>(degc, partial, starts, N2);
    csr_fill_all<<<gE, blk, 0, stream>>>(ei1, ei2, dinv1, dinv2, starts, degc, csr, N, E1, E2);

    // ---- R0 = relu(x @ W_in + b_in); outacc = w0*readout0 + CONST ----
    mm_in<<<gMM, blk, 0, stream>>>(x, W_in, b_in, R0, Wr0, br0, br1, br2,
                                   w0, w1, w2, w3, c3, outacc, N);

    // ---- layer 1 ----
    mm64b<64><<<gMM, blk, 0, stream>>>(R0, W11, Y16_L1, 0, N);
    mm64b<64><<<gMM, blk, 0, stream>>>(R0, W12, Y16_L1, 64, N);
    gatherRO<<<gGa, blk, 0, stream>>>(starts, csr, Y16_L1, b11, b12, P, Wr1, w1, outacc, N);

    // ---- layer 2 ----
    mm64b<128><<<gMM, blk, 0, stream>>>(P, W21, Y16_L2, 0, N);
    mm64b<128><<<gMM, blk, 0, stream>>>(P, W22, Y16_L2, 64, N);
    gatherRO<<<gGa, blk, 0, stream>>>(starts, csr, Y16_L2, b21, b22, Q, Wr2, w2, outacc, N);

    // ---- layer 3 (algebraic shortcut): out3 = w3*(sum_e wt*z[src] + c3) ----
    zpair<<<gZ, blk, 0, stream>>>(Q, u31, u32v, w3, z1, z2, N);
    edge3<<<gE, blk, 0, stream>>>(ei1, ei2, dinv1, dinv2, z1, z2, outacc, E1, E2);
    finalize<<<gN, blk, 0, stream>>>(outacc, (float*)d_out, N);
}

// Round 7
// 528.901 us; speedup vs baseline: 1.5826x; 1.1836x over previous
//
#include <hip/hip_runtime.h>
#include <cstdint>
#include <cstddef>

typedef unsigned short u16;
typedef unsigned int u32;

__device__ __forceinline__ u16 f2b(float f) {
    u32 b = __float_as_uint(f);
    b += 0x7fffu + ((b >> 16) & 1u);   // RNE
    return (u16)(b >> 16);
}
__device__ __forceinline__ float b2f(u16 u) {
    return __uint_as_float(((u32)u) << 16);
}

// ================= u-precompute: u31 = W31@Wr3[0:64], u32 = W32@Wr3[64:128], c3 =================
__global__ void uprep(const float* __restrict__ W31, const float* __restrict__ W32,
                      const float* __restrict__ b31, const float* __restrict__ b32,
                      const float* __restrict__ Wr3, const float* __restrict__ br3,
                      float* __restrict__ u31, float* __restrict__ u32, float* __restrict__ c3) {
    __shared__ float s[64];
    int t = threadIdx.x;
    if (t < 128) {
        float a = 0.f, b = 0.f;
        for (int c = 0; c < 64; ++c) {
            a = fmaf(W31[t * 64 + c], Wr3[c], a);
            b = fmaf(W32[t * 64 + c], Wr3[64 + c], b);
        }
        u31[t] = a;
        u32[t] = b;
    }
    if (t < 64) s[t] = b31[t] * Wr3[t] + b32[t] * Wr3[64 + t];
    __syncthreads();
    if (t < 32) s[t] += s[t + 32];
    __syncthreads();
    if (t == 0) {
        float acc = 0.f;
        for (int i = 0; i < 32; ++i) acc += s[i];
        c3[0] = acc + br3[0];
    }
}

// ================= CSR build =================
__global__ void degcnt_all(const int* __restrict__ c1, const int* __restrict__ c2,
                           int* __restrict__ degc, int N, int E1, int E2) {
    int e = blockIdx.x * blockDim.x + threadIdx.x;
    if (e < E1) atomicAdd(&degc[c1[e]], 1);
    else if (e < E1 + E2) atomicAdd(&degc[N + c2[e - E1]], 1);
}

__global__ void dinv_fin(const int* __restrict__ degc, float* __restrict__ d1,
                         float* __restrict__ d2, int n) {
    int i = blockIdx.x * blockDim.x + threadIdx.x;
    if (i < n) {
        int a = degc[i], b = degc[n + i];
        d1[i] = a > 0 ? rsqrtf((float)a) : 0.f;
        d2[i] = b > 0 ? rsqrtf((float)b) : 0.f;
    }
}

__global__ void scan1(const int* __restrict__ deg, int* __restrict__ partial, int n) {
    __shared__ int s[256];
    int i = blockIdx.x * 256 + threadIdx.x;
    s[threadIdx.x] = (i < n) ? deg[i] : 0;
    __syncthreads();
    for (int off = 128; off > 0; off >>= 1) {
        if (threadIdx.x < off) s[threadIdx.x] += s[threadIdx.x + off];
        __syncthreads();
    }
    if (threadIdx.x == 0) partial[blockIdx.x] = s[0];
}

__global__ void scan2(int* __restrict__ partial, int nb, int* __restrict__ starts, int n) {
    __shared__ int s[512];
    int t = threadIdx.x;
    int v = (t < nb) ? partial[t] : 0;
    s[t] = v;
    __syncthreads();
    for (int off = 1; off < 512; off <<= 1) {
        int u = (t >= off) ? s[t - off] : 0;
        __syncthreads();
        s[t] += u;
        __syncthreads();
    }
    if (t < nb) partial[t] = s[t] - v;
    if (t == 511) starts[n] = s[511];
}

__global__ void scan3(const int* __restrict__ deg, const int* __restrict__ partial,
                      int* __restrict__ starts, int n) {
    __shared__ int s[256];
    int i = blockIdx.x * 256 + threadIdx.x;
    int v = (i < n) ? deg[i] : 0;
    s[threadIdx.x] = v;
    __syncthreads();
    for (int off = 1; off < 256; off <<= 1) {
        int u = (threadIdx.x >= off) ? s[threadIdx.x - off] : 0;
        __syncthreads();
        s[threadIdx.x] += u;
        __syncthreads();
    }
    if (i < n) starts[i] = partial[blockIdx.x] + s[threadIdx.x] - v;
}

// fill CSR slots; reuses degc as countdown cursor (degc dead after scans)
__global__ void csr_fill_all(const int* __restrict__ ei1, const int* __restrict__ ei2,
                             const float* __restrict__ dinv1, const float* __restrict__ dinv2,
                             const int* __restrict__ starts, int* __restrict__ degc,
                             int2* __restrict__ csr, int N, int E1, int E2) {
    int e = blockIdx.x * blockDim.x + threadIdx.x;
    int r, c, base;
    const float* dinv;
    if (e < E1) { r = ei1[e]; c = ei1[E1 + e]; base = 0; dinv = dinv1; }
    else if (e < E1 + E2) { int t = e - E1; r = ei2[t]; c = ei2[E2 + t]; base = N; dinv = dinv2; }
    else return;
    int pos = starts[base + c] + atomicSub(&degc[base + c], 1) - 1;
    csr[pos] = make_int2(r, __float_as_int(dinv[r] * dinv[c]));
}

// ================= mm_in: R0 = relu(x@W_in + b_in); fused readout0 + outacc init =================
__global__ __launch_bounds__(256) void mm_in(const float* __restrict__ A, const float* __restrict__ W,
                                             const float* __restrict__ bias, float* __restrict__ C,
                                             const float* __restrict__ Wr0, const float* __restrict__ br0,
                                             const float* __restrict__ br1, const float* __restrict__ br2,
                                             const float* __restrict__ w0, const float* __restrict__ w1,
                                             const float* __restrict__ w2, const float* __restrict__ w3,
                                             const float* __restrict__ c3, float* __restrict__ outacc,
                                             int n) {
    __shared__ float As[64][68];
    __shared__ float Ws[64][68];
    const int tid = threadIdx.x;
    const int r0 = blockIdx.x * 64;

    for (int idx = tid; idx < 64 * 16; idx += 256) {
        int k = idx >> 4, cq = (idx & 15) * 4;
        *(float4*)&Ws[k][cq] = *(const float4*)&W[k * 64 + cq];
    }

    const int tr = (tid >> 4) * 4;
    const int tc = (tid & 15) * 4;
    float4 acc0 = {0,0,0,0}, acc1 = {0,0,0,0}, acc2 = {0,0,0,0}, acc3 = {0,0,0,0};

    __syncthreads();
#pragma unroll
    for (int it = 0; it < 4; ++it) {
        int r = (tid >> 4) + it * 16;
        int cq = (tid & 15) * 4;
        int gr = r0 + r;
        float4 v = {0,0,0,0};
        if (gr < n) v = *(const float4*)&A[(size_t)gr * 64 + cq];
        *(float4*)&As[r][cq] = v;
    }
    __syncthreads();
#pragma unroll
    for (int k = 0; k < 64; k += 4) {
        float4 a0 = *(const float4*)&As[tr + 0][k];
        float4 a1 = *(const float4*)&As[tr + 1][k];
        float4 a2 = *(const float4*)&As[tr + 2][k];
        float4 a3 = *(const float4*)&As[tr + 3][k];
        float4 b0 = *(const float4*)&Ws[k + 0][tc];
        float4 b1 = *(const float4*)&Ws[k + 1][tc];
        float4 b2 = *(const float4*)&Ws[k + 2][tc];
        float4 b3 = *(const float4*)&Ws[k + 3][tc];
#define DK(comp, B)                                                                   \
        acc0.x = fmaf(a0.comp, B.x, acc0.x); acc0.y = fmaf(a0.comp, B.y, acc0.y);     \
        acc0.z = fmaf(a0.comp, B.z, acc0.z); acc0.w = fmaf(a0.comp, B.w, acc0.w);     \
        acc1.x = fmaf(a1.comp, B.x, acc1.x); acc1.y = fmaf(a1.comp, B.y, acc1.y);     \
        acc1.z = fmaf(a1.comp, B.z, acc1.z); acc1.w = fmaf(a1.comp, B.w, acc1.w);     \
        acc2.x = fmaf(a2.comp, B.x, acc2.x); acc2.y = fmaf(a2.comp, B.y, acc2.y);     \
        acc2.z = fmaf(a2.comp, B.z, acc2.z); acc2.w = fmaf(a2.comp, B.w, acc2.w);     \
        acc3.x = fmaf(a3.comp, B.x, acc3.x); acc3.y = fmaf(a3.comp, B.y, acc3.y);     \
        acc3.z = fmaf(a3.comp, B.z, acc3.z); acc3.w = fmaf(a3.comp, B.w, acc3.w);
        DK(x, b0) DK(y, b1) DK(z, b2) DK(w, b3)
#undef DK
    }

    float4 bv = *(const float4*)&bias[tc];
    float4 wr = *(const float4*)&Wr0[tc];
    float4 accs[4] = {acc0, acc1, acc2, acc3};
    float part[4];
#pragma unroll
    for (int i = 0; i < 4; ++i) {
        float4 v = accs[i];
        v.x = fmaxf(v.x + bv.x, 0.f); v.y = fmaxf(v.y + bv.y, 0.f);
        v.z = fmaxf(v.z + bv.z, 0.f); v.w = fmaxf(v.w + bv.w, 0.f);
        int gr = r0 + tr + i;
        if (gr < n) *(float4*)&C[(size_t)gr * 64 + tc] = v;
        part[i] = v.x * wr.x + v.y * wr.y + v.z * wr.z + v.w * wr.w;
    }
#pragma unroll
    for (int off = 8; off > 0; off >>= 1) {
#pragma unroll
        for (int i = 0; i < 4; ++i) part[i] += __shfl_down(part[i], off);
    }
    if ((tid & 15) == 0) {
        float W0 = w0[0];
        float CONST = W0 * br0[0] + w1[0] * br1[0] + w2[0] * br2[0] + w3[0] * c3[0];
#pragma unroll
        for (int i = 0; i < 4; ++i) {
            int gr = r0 + tr + i;
            if (gr < n) outacc[gr] = W0 * part[i] + CONST;
        }
    }
}

// ================= mm64b: Y16[:, coff:coff+64] = A @ W (bf16 out, row stride 128) =================
template <int K>
__global__ __launch_bounds__(256) void mm64b(const float* __restrict__ A, const float* __restrict__ W,
                                             u16* __restrict__ Y16, int coff, int n) {
    __shared__ float As[64][68];
    __shared__ float Ws[K][68];
    const int tid = threadIdx.x;
    const int r0 = blockIdx.x * 64;

    for (int idx = tid; idx < K * 16; idx += 256) {
        int k = idx >> 4, cq = (idx & 15) * 4;
        *(float4*)&Ws[k][cq] = *(const float4*)&W[k * 64 + cq];
    }

    const int tr = (tid >> 4) * 4;
    const int tc = (tid & 15) * 4;
    float4 acc0 = {0,0,0,0}, acc1 = {0,0,0,0}, acc2 = {0,0,0,0}, acc3 = {0,0,0,0};

    for (int kb = 0; kb < K; kb += 64) {
        __syncthreads();
#pragma unroll
        for (int it = 0; it < 4; ++it) {
            int r = (tid >> 4) + it * 16;
            int cq = (tid & 15) * 4;
            int gr = r0 + r;
            float4 v = {0,0,0,0};
            if (gr < n) v = *(const float4*)&A[(size_t)gr * K + kb + cq];
            *(float4*)&As[r][cq] = v;
        }
        __syncthreads();
#pragma unroll
        for (int k = 0; k < 64; k += 4) {
            float4 a0 = *(const float4*)&As[tr + 0][k];
            float4 a1 = *(const float4*)&As[tr + 1][k];
            float4 a2 = *(const float4*)&As[tr + 2][k];
            float4 a3 = *(const float4*)&As[tr + 3][k];
            float4 b0 = *(const float4*)&Ws[kb + k + 0][tc];
            float4 b1 = *(const float4*)&Ws[kb + k + 1][tc];
            float4 b2 = *(const float4*)&Ws[kb + k + 2][tc];
            float4 b3 = *(const float4*)&Ws[kb + k + 3][tc];
#define DK(comp, B)                                                                   \
            acc0.x = fmaf(a0.comp, B.x, acc0.x); acc0.y = fmaf(a0.comp, B.y, acc0.y); \
            acc0.z = fmaf(a0.comp, B.z, acc0.z); acc0.w = fmaf(a0.comp, B.w, acc0.w); \
            acc1.x = fmaf(a1.comp, B.x, acc1.x); acc1.y = fmaf(a1.comp, B.y, acc1.y); \
            acc1.z = fmaf(a1.comp, B.z, acc1.z); acc1.w = fmaf(a1.comp, B.w, acc1.w); \
            acc2.x = fmaf(a2.comp, B.x, acc2.x); acc2.y = fmaf(a2.comp, B.y, acc2.y); \
            acc2.z = fmaf(a2.comp, B.z, acc2.z); acc2.w = fmaf(a2.comp, B.w, acc2.w); \
            acc3.x = fmaf(a3.comp, B.x, acc3.x); acc3.y = fmaf(a3.comp, B.y, acc3.y); \
            acc3.z = fmaf(a3.comp, B.z, acc3.z); acc3.w = fmaf(a3.comp, B.w, acc3.w);
            DK(x, b0) DK(y, b1) DK(z, b2) DK(w, b3)
#undef DK
        }
    }

    float4 accs[4] = {acc0, acc1, acc2, acc3};
#pragma unroll
    for (int i = 0; i < 4; ++i) {
        int gr = r0 + tr + i;
        if (gr < n) {
            ushort4 o;
            o.x = f2b(accs[i].x); o.y = f2b(accs[i].y); o.z = f2b(accs[i].z); o.w = f2b(accs[i].w);
            *(ushort4*)&Y16[(size_t)gr * 128 + coff + tc] = o;
        }
    }
}

// ================= gather + fused readout (+ optional z-projection, optional dest store) ==========
// wave = (dest, set); half-waves process even/odd edges; lane pairs 2 channels via u32.
template <bool STORE, bool ZCOMP>
__global__ __launch_bounds__(256) void gatherRO(const int* __restrict__ starts,
                                                const int2* __restrict__ csr,
                                                const u16* __restrict__ Y16,
                                                const float* __restrict__ bA,
                                                const float* __restrict__ bB,
                                                float* __restrict__ dest,
                                                const float* __restrict__ Wr,
                                                const float* __restrict__ wl,
                                                const float* __restrict__ u31,
                                                const float* __restrict__ u32v,
                                                const float* __restrict__ w3,
                                                float* __restrict__ z1,
                                                float* __restrict__ z2,
                                                float* __restrict__ outacc, int N) {
    int wave = (blockIdx.x * blockDim.x + threadIdx.x) >> 6;
    int lane = threadIdx.x & 63;
    if (wave >= 2 * N) return;
    int set2 = wave >= N;
    int d = set2 ? wave - N : wave;
    int base = set2 ? N : 0;
    int yoff = set2 ? 64 : 0;
    int half = lane >> 5;       // 0 or 1
    int m = lane & 31;          // channel-pair index

    int s0 = __builtin_amdgcn_readfirstlane(starts[base + d]);
    int s1 = __builtin_amdgcn_readfirstlane(starts[base + d + 1]);

    float ax = 0.f, ay = 0.f;
    int j = s0;
    for (; j + 8 <= s1; j += 8) {
        int2 e0 = csr[j + half];
        int2 e1 = csr[j + 2 + half];
        int2 e2 = csr[j + 4 + half];
        int2 e3 = csr[j + 6 + half];
        u32 y0 = *(const u32*)&Y16[(size_t)e0.x * 128 + yoff + 2 * m];
        u32 y1 = *(const u32*)&Y16[(size_t)e1.x * 128 + yoff + 2 * m];
        u32 y2 = *(const u32*)&Y16[(size_t)e2.x * 128 + yoff + 2 * m];
        u32 y3 = *(const u32*)&Y16[(size_t)e3.x * 128 + yoff + 2 * m];
        float w0 = __int_as_float(e0.y), w1 = __int_as_float(e1.y);
        float w2 = __int_as_float(e2.y), w3e = __int_as_float(e3.y);
        ax = fmaf(w0, b2f((u16)y0), ax); ay = fmaf(w0, b2f((u16)(y0 >> 16)), ay);
        ax = fmaf(w1, b2f((u16)y1), ax); ay = fmaf(w1, b2f((u16)(y1 >> 16)), ay);
        ax = fmaf(w2, b2f((u16)y2), ax); ay = fmaf(w2, b2f((u16)(y2 >> 16)), ay);
        ax = fmaf(w3e, b2f((u16)y3), ax); ay = fmaf(w3e, b2f((u16)(y3 >> 16)), ay);
    }
    if (j + 4 <= s1) {
        int2 e0 = csr[j + half];
        int2 e1 = csr[j + 2 + half];
        u32 y0 = *(const u32*)&Y16[(size_t)e0.x * 128 + yoff + 2 * m];
        u32 y1 = *(const u32*)&Y16[(size_t)e1.x * 128 + yoff + 2 * m];
        float w0 = __int_as_float(e0.y), w1 = __int_as_float(e1.y);
        ax = fmaf(w0, b2f((u16)y0), ax); ay = fmaf(w0, b2f((u16)(y0 >> 16)), ay);
        ax = fmaf(w1, b2f((u16)y1), ax); ay = fmaf(w1, b2f((u16)(y1 >> 16)), ay);
        j += 4;
    }
    if (j + 2 <= s1) {
        int2 e = csr[j + half];
        u32 y = *(const u32*)&Y16[(size_t)e.x * 128 + yoff + 2 * m];
        float w = __int_as_float(e.y);
        ax = fmaf(w, b2f((u16)y), ax); ay = fmaf(w, b2f((u16)(y >> 16)), ay);
        j += 2;
    }
    if (j < s1 && half == 0) {
        int2 e = csr[j];
        u32 y = *(const u32*)&Y16[(size_t)e.x * 128 + yoff + 2 * m];
        float w = __int_as_float(e.y);
        ax = fmaf(w, b2f((u16)y), ax); ay = fmaf(w, b2f((u16)(y >> 16)), ay);
    }
    // combine halves
    ax += __shfl_down(ax, 32);
    ay += __shfl_down(ay, 32);

    if (half == 0) {
        const float* bias = set2 ? bB : bA;
        float bx = bias[2 * m], by = bias[2 * m + 1];
        float vx = ax + bx, vy = ay + by;
        if (STORE)
            *(float2*)&dest[(size_t)d * 128 + yoff + 2 * m] = make_float2(vx, vy);
        float p = vx * Wr[yoff + 2 * m] + vy * Wr[yoff + 2 * m + 1];
        float p1 = 0.f, p2 = 0.f;
        if (ZCOMP) {
            p1 = vx * u31[yoff + 2 * m] + vy * u31[yoff + 2 * m + 1];
            p2 = vx * u32v[yoff + 2 * m] + vy * u32v[yoff + 2 * m + 1];
        }
#pragma unroll
        for (int off = 16; off > 0; off >>= 1) {
            p += __shfl_down(p, off);
            if (ZCOMP) { p1 += __shfl_down(p1, off); p2 += __shfl_down(p2, off); }
        }
        if (m == 0) {
            atomicAdd(&outacc[d], wl[0] * p);
            if (ZCOMP) {
                float W3 = w3[0];
                atomicAdd(&z1[d], W3 * p1);
                atomicAdd(&z2[d], W3 * p2);
            }
        }
    }
}

// ================= gather3: out[d] = outacc[d] + sum_e1 wt*z1[src] + sum_e2 wt*z2[src] ============
__global__ __launch_bounds__(256) void gather3(const int* __restrict__ starts,
                                               const int2* __restrict__ csr,
                                               const float* __restrict__ z1,
                                               const float* __restrict__ z2,
                                               const float* __restrict__ outacc,
                                               float* __restrict__ out, int N) {
    int d = (blockIdx.x * blockDim.x + threadIdx.x) >> 6;
    int lane = threadIdx.x & 63;
    if (d >= N) return;
    int a0 = __builtin_amdgcn_readfirstlane(starts[d]);
    int a1 = __builtin_amdgcn_readfirstlane(starts[d + 1]);
    int b0 = __builtin_amdgcn_readfirstlane(starts[N + d]);
    int b1 = __builtin_amdgcn_readfirstlane(starts[N + d + 1]);
    float acc = 0.f;
    for (int j = a0 + lane; j < a1; j += 64) {
        int2 e = csr[j];
        acc = fmaf(__int_as_float(e.y), z1[e.x], acc);
    }
    for (int j = b0 + lane; j < b1; j += 64) {
        int2 e = csr[j];
        acc = fmaf(__int_as_float(e.y), z2[e.x], acc);
    }
#pragma unroll
    for (int off = 32; off > 0; off >>= 1) acc += __shfl_down(acc, off);
    if (lane == 0) out[d] = outacc[d] + acc;
}

// ================= host =================
static inline char* carve(char*& p, size_t bytes) {
    char* r = p;
    p += (bytes + 255) & ~(size_t)255;
    return r;
}

extern "C" void kernel_launch(void* const* d_in, const int* in_sizes, int n_in,
                              void* d_out, int out_size, void* d_ws, size_t ws_size,
                              hipStream_t stream) {
    const float* x    = (const float*)d_in[0];
    const int*   ei1  = (const int*)d_in[1];
    const int*   ei2  = (const int*)d_in[2];
    const float* W_in = (const float*)d_in[3];  const float* b_in = (const float*)d_in[4];
    const float* W11  = (const float*)d_in[5];
    const float* b11  = (const float*)d_in[6];
    const float* W12  = (const float*)d_in[7];  const float* b12  = (const float*)d_in[8];
    const float* W21  = (const float*)d_in[9];  const float* b21  = (const float*)d_in[10];
    const float* W22  = (const float*)d_in[11]; const float* b22  = (const float*)d_in[12];
    const float* W31  = (const float*)d_in[13]; const float* b31  = (const float*)d_in[14];
    const float* W32  = (const float*)d_in[15]; const float* b32  = (const float*)d_in[16];
    const float* Wr0  = (const float*)d_in[17]; const float* br0  = (const float*)d_in[18];
    const float* Wr1  = (const float*)d_in[19]; const float* br1  = (const float*)d_in[20];
    const float* Wr2  = (const float*)d_in[21]; const float* br2  = (const float*)d_in[22];
    const float* Wr3  = (const float*)d_in[23]; const float* br3  = (const float*)d_in[24];
    const float* w0   = (const float*)d_in[25];
    const float* w1   = (const float*)d_in[26];
    const float* w2   = (const float*)d_in[27];
    const float* w3   = (const float*)d_in[28];

    const int N  = in_sizes[0] / 64;   // 50000
    const int E1 = in_sizes[1] / 2;    // 800000
    const int E2 = in_sizes[2] / 2;
    const int N2 = 2 * N;

    char* p = (char*)d_ws;
    float* dinv1   = (float*)carve(p, (size_t)N * 4);
    float* dinv2   = (float*)carve(p, (size_t)N * 4);
    int*   degc    = (int*)  carve(p, (size_t)N2 * 4);
    int*   starts  = (int*)  carve(p, ((size_t)N2 + 1) * 4);
    int*   partial = (int*)  carve(p, 512 * 4);
    float* uws     = (float*)carve(p, (128 + 128 + 1) * 4);  // u31, u32, c3
    float* z       = (float*)carve(p, (size_t)N2 * 4);       // z1 | z2 contiguous
    int2*  csr     = (int2*) carve(p, (size_t)(E1 + E2) * 8);
    float* R0      = (float*)carve(p, (size_t)N * 64 * 4);
    float* P       = (float*)carve(p, (size_t)N * 128 * 4);
    u16*   Y16     = (u16*)  carve(p, (size_t)N * 128 * 2);
    float* outacc  = (float*)carve(p, (size_t)N * 4);
    float* u31 = uws, *u32v = uws + 128, *c3 = uws + 256;
    float* z1 = z, *z2 = z + N;
    (void)ws_size; (void)n_in; (void)out_size;

    const int B = 256;
    dim3 blk(B);
    int gN   = (N + B - 1) / B;
    int gE   = (E1 + E2 + B - 1) / B;
    int gMM  = (N + 63) / 64;
    int gGa  = (int)(((long long)N2 * 64 + B - 1) / B);
    int gG3  = (int)(((long long)N * 64 + B - 1) / B);
    int nb   = (N2 + 255) / 256;

    // ---- CSR build + u-precompute ----
    hipMemsetAsync(degc, 0, (size_t)N2 * 4, stream);
    hipMemsetAsync(z, 0, (size_t)N2 * 4, stream);
    uprep<<<1, 128, 0, stream>>>(W31, W32, b31, b32, Wr3, br3, u31, u32v, c3);
    degcnt_all<<<gE, blk, 0, stream>>>(ei1 + E1, ei2 + E2, degc, N, E1, E2);
    dinv_fin<<<gN, blk, 0, stream>>>(degc, dinv1, dinv2, N);
    scan1<<<nb, blk, 0, stream>>>(degc, partial, N2);
    scan2<<<1, 512, 0, stream>>>(partial, nb, starts, N2);
    scan3<<<nb, blk, 0, stream>>>(degc, partial, starts, N2);
    csr_fill_all<<<gE, blk, 0, stream>>>(ei1, ei2, dinv1, dinv2, starts, degc, csr, N, E1, E2);

    // ---- R0 = relu(x @ W_in + b_in); outacc = w0*readout0 + CONST ----
    mm_in<<<gMM, blk, 0, stream>>>(x, W_in, b_in, R0, Wr0, br0, br1, br2,
                                   w0, w1, w2, w3, c3, outacc, N);

    // ---- layer 1: P = R1; readout1 fused ----
    mm64b<64><<<gMM, blk, 0, stream>>>(R0, W11, Y16, 0, N);
    mm64b<64><<<gMM, blk, 0, stream>>>(R0, W12, Y16, 64, N);
    gatherRO<true, false><<<gGa, blk, 0, stream>>>(starts, csr, Y16, b11, b12, P, Wr1, w1,
                                                   u31, u32v, w3, z1, z2, outacc, N);

    // ---- layer 2: Q never materialized; readout2 + z-projection fused ----
    mm64b<128><<<gMM, blk, 0, stream>>>(P, W21, Y16, 0, N);
    mm64b<128><<<gMM, blk, 0, stream>>>(P, W22, Y16, 64, N);
    gatherRO<false, true><<<gGa, blk, 0, stream>>>(starts, csr, Y16, b21, b22, nullptr, Wr2, w2,
                                                   u31, u32v, w3, z1, z2, outacc, N);

    // ---- layer 3 (algebraic shortcut): out = outacc + gather(z) ----
    gather3<<<gG3, blk, 0, stream>>>(starts, csr, z1, z2, outacc, (float*)d_out, N);
}